// Round 1
// baseline (223.945 us; speedup 1.0000x reference)
//
#include <hip/hip_runtime.h>
#include <hip/hip_fp16.h>

// Problem: inputs (8, 64, 16, 32, 32) fp32, embedding (1024, 64) fp32
#define THW    16384
#define NTOT   131072
#define KDIM   1024
#define CDIM   64
#define QELEMS 8388608          // 8*64*16*32*32
#define LOSS_OFF 8388608
#define IDX_OFF  8388610
#define BN     128              // queries per block (4 waves x 32 queries)

typedef _Float16 half8   __attribute__((ext_vector_type(8)));
typedef _Float16 half4_t __attribute__((ext_vector_type(4)));
typedef float    f32x4   __attribute__((ext_vector_type(4)));

// ---- prep: zero losses; split E into fp16 hi/lo (lo scaled 2^12) into ONE
// interleaved buffer Ef[tile][hl*2+ch][lane][8] so the main loop's 4 A-loads
// share a single base pointer with 0/1024/2048/3072 B immediate offsets.
// lane = lq*16 + ln, code row = tile*16 + ln, c = ch*32 + lq*8 + j.
// Stores me2h[row] = -0.5*||e||^2 (seed for the hh MFMA chain).
__global__ __launch_bounds__(256) void vq_prep(const float* __restrict__ emb,
        _Float16* __restrict__ Ef, float* __restrict__ me2h,
        float* __restrict__ out) {
    const int t = threadIdx.x;
    if (blockIdx.x == 0 && t == 0) { out[LOSS_OFF] = 0.f; out[LOSS_OFF + 1] = 0.f; }
    const int ln   = t >> 4;
    const int g    = t & 15;
    const int tile = blockIdx.x;
    const int row  = tile * 16 + ln;
    const int c0   = g * 4;
    float4 v = *(const float4*)(emb + (size_t)row * CDIM + c0);
    const float xs[4] = {v.x, v.y, v.z, v.w};
    half4_t h, l;
    float s = 0.f;
    #pragma unroll
    for (int j = 0; j < 4; ++j) {
        const _Float16 hj = (_Float16)xs[j];
        const _Float16 lj = (_Float16)((xs[j] - (float)hj) * 4096.0f);
        h[j] = hj; l[j] = lj;
        s = fmaf(xs[j], xs[j], s);
    }
    const int ch = c0 >> 5;
    const int lq = (c0 & 31) >> 3;
    const int j0 = c0 & 7;
    const int fl = lq * 16 + ln;
    *(half4_t*)(Ef + (((size_t)tile * 4 + ch)     * 64 + fl) * 8 + j0) = h;
    *(half4_t*)(Ef + (((size_t)tile * 4 + 2 + ch) * 64 + fl) * 8 + j0) = l;
    #pragma unroll
    for (int off = 1; off < 16; off <<= 1) s += __shfl_xor(s, off, 64);
    if (g == 0) me2h[row] = -0.5f * s;
}

// ---- main: ZERO LDS, ZERO barriers. Each lane loads its own 32 B-fragment
// floats directly from global (64B-coalesced across ln); waves are fully
// independent; epilogue index lives in-register; loss via per-wave atomics.
__global__ __launch_bounds__(256, 4) void vq_main(const float* __restrict__ in,
        const float* __restrict__ emb,
        const _Float16* __restrict__ Ef,
        const float* __restrict__ me2h, float* __restrict__ out) {

    const int tid  = threadIdx.x;
    const int n0   = blockIdx.x * BN;
    const int bb   = n0 >> 14;
    const int thw0 = n0 & (THW - 1);
    const float* inb = in  + (size_t)bb * CDIM * THW + thw0;
    float*      outb = out + (size_t)bb * CDIM * THW + thw0;

    const int lane = tid & 63;
    const int w    = tid >> 6;      // wave owns queries w*32 .. w*32+31
    const int ln   = lane & 15;
    const int lq   = lane >> 4;

    // ---- direct global→reg staging + fp16 hi/lo split (no LDS round-trip).
    // Lane (ln,lq) needs X[q][ch*32+lq*8+j] for q = w*32+qg*16+ln — load it
    // straight: for fixed (ch,j), the 16 ln-lanes read 64 contiguous bytes.
    half8 Bh[2][2], Bl[2][2];
    float x2r[2];                   // full ||x||^2 of my qg-row (all lanes)
    #pragma unroll
    for (int qg = 0; qg < 2; ++qg) {
        const int n = w * 32 + qg * 16 + ln;
        const float* bp = inb + (size_t)lq * 8 * THW + n;
        float xv[16];
        #pragma unroll
        for (int ch = 0; ch < 2; ++ch)
            #pragma unroll
            for (int j = 0; j < 8; ++j)
                xv[ch * 8 + j] = bp[(size_t)(ch * 32 + j) * THW];
        float s = 0.f;
        #pragma unroll
        for (int ch = 0; ch < 2; ++ch) {
            #pragma unroll
            for (int j = 0; j < 8; ++j) {
                const float x = xv[ch * 8 + j];
                const _Float16 h = (_Float16)x;
                Bh[qg][ch][j] = h;
                Bl[qg][ch][j] = (_Float16)((x - (float)h) * 4096.0f);
                s = fmaf(x, x, s);
            }
        }
        s += __shfl_xor(s, 16, 64);     // sum over the 4 lq quads
        s += __shfl_xor(s, 32, 64);
        x2r[qg] = s;
    }

    // maximize s = x.e - 0.5*||e||^2  (argmax s == argmin d, d = -2s)
    float bests[2] = {-3.4e38f, -3.4e38f};
    int   besti[2] = {0, 0};

    const half8* pa  = (const half8*)Ef + lane;     // tile m at +m*256
    const f32x4* pe4 = (const f32x4*)me2h + lq;     // tile m at +m*4

    // depth-1 prefetch, 2 buffers; Ah0/Ah1/Al0/Al1 at +0/64/128/192 half8s
    half8 Ah0[2], Ah1[2], Al0[2], Al1[2];
    f32x4 e2r[2];
    Ah0[0] = pa[0];   Ah1[0] = pa[64];
    Al0[0] = pa[128]; Al1[0] = pa[192];
    e2r[0] = pe4[0];

    #pragma unroll 2
    for (int m = 0; m < 64; ++m) {
        const int cur = m & 1;
        const int nxt = cur ^ 1;
        if (m < 63) {
            const size_t o = (size_t)(m + 1) * 256;
            Ah0[nxt] = pa[o];       Ah1[nxt] = pa[o + 64];
            Al0[nxt] = pa[o + 128]; Al1[nxt] = pa[o + 192];
            e2r[nxt] = pe4[(m + 1) * 4];
        }
        #pragma unroll
        for (int qg = 0; qg < 2; ++qg) {
            // cross terms first (scaled 2^12)
            f32x4 a1 = {0.f, 0.f, 0.f, 0.f};
            a1 = __builtin_amdgcn_mfma_f32_16x16x32_f16(Ah0[cur], Bl[qg][0], a1, 0, 0, 0);
            a1 = __builtin_amdgcn_mfma_f32_16x16x32_f16(Al0[cur], Bh[qg][0], a1, 0, 0, 0);
            a1 = __builtin_amdgcn_mfma_f32_16x16x32_f16(Ah1[cur], Bl[qg][1], a1, 0, 0, 0);
            a1 = __builtin_amdgcn_mfma_f32_16x16x32_f16(Al1[cur], Bh[qg][1], a1, 0, 0, 0);
            // seed hh-chain with 2^-12*a1 - 0.5*||e||^2
            f32x4 c0;
            #pragma unroll
            for (int r = 0; r < 4; ++r)
                c0[r] = fmaf(2.44140625e-4f, a1[r], e2r[cur][r]);
            c0 = __builtin_amdgcn_mfma_f32_16x16x32_f16(Ah0[cur], Bh[qg][0], c0, 0, 0, 0);
            c0 = __builtin_amdgcn_mfma_f32_16x16x32_f16(Ah1[cur], Bh[qg][1], c0, 0, 0, 0);
            // fold: bare compare (ascending k, strict > keeps lowest k)
            #pragma unroll
            for (int r = 0; r < 4; ++r) {
                const int kg = m * 16 + lq * 4 + r;
                if (c0[r] > bests[qg]) { bests[qg] = c0[r]; besti[qg] = kg; }
            }
        }
    }

    // ---- wave-internal argmax reduce across the 4 row-quads ----
    #pragma unroll
    for (int qg = 0; qg < 2; ++qg) {
        #pragma unroll
        for (int msk = 16; msk <= 32; msk <<= 1) {
            const float ov = __shfl_xor(bests[qg], msk, 64);
            const int   oi = __shfl_xor(besti[qg], msk, 64);
            if (ov > bests[qg] || (ov == bests[qg] && oi < besti[qg])) {
                bests[qg] = ov; besti[qg] = oi;
            }
        }
    }

    // ---- loss: per-wave reduce + atomic (no LDS, no barrier) ----
    float lsum = 0.f;
    if (lq == 0) {
        #pragma unroll
        for (int qg = 0; qg < 2; ++qg)
            lsum += fmaf(-2.0f, bests[qg], x2r[qg]);    // d = -2s + ||x||^2
    }
    #pragma unroll
    for (int off = 32; off > 0; off >>= 1) lsum += __shfl_down(lsum, off, 64);
    if (lane == 0) {
        atomicAdd(&out[LOSS_OFF],     lsum * (1.0f  / (float)QELEMS));
        atomicAdd(&out[LOSS_OFF + 1], lsum * (0.25f / (float)QELEMS));
    }

    // ---- epilogue: index is already in-register for every lane ----
    // lane handles query qc = lane&31 (qg' = (lane>>4)&1 matches its own ln),
    // c-half chh = lane>>5; stores are 2x128B-coalesced per instruction.
    {
        const int qc    = lane & 31;
        const int chh   = lane >> 5;
        const int myidx = besti[(lane >> 4) & 1];
        if (chh == 0) out[IDX_OFF + n0 + w * 32 + qc] = (float)myidx;
        const float* er = emb + (size_t)myidx * CDIM + chh * 32;
        float* ob = outb + w * 32 + qc;
        #pragma unroll
        for (int cq = 0; cq < 8; ++cq) {
            const float4 v = *(const float4*)(er + 4 * cq);
            ob[(size_t)(chh * 32 + 4 * cq + 0) * THW] = v.x;
            ob[(size_t)(chh * 32 + 4 * cq + 1) * THW] = v.y;
            ob[(size_t)(chh * 32 + 4 * cq + 2) * THW] = v.z;
            ob[(size_t)(chh * 32 + 4 * cq + 3) * THW] = v.w;
        }
    }
}

extern "C" void kernel_launch(void* const* d_in, const int* in_sizes, int n_in,
                              void* d_out, int out_size, void* d_ws, size_t ws_size,
                              hipStream_t stream) {
    const float* in  = (const float*)d_in[0];   // (8, 64, 16, 32, 32) fp32
    const float* emb = (const float*)d_in[1];   // (1024, 64) fp32
    float* out = (float*)d_out;
    _Float16* Ef   = (_Float16*)d_ws;                       // 64 tiles * 4 * 64 * 8 halves = 256 KB
    float*    me2h = (float*)((char*)d_ws + 262144);        // 1024 floats = -0.5*||e||^2

    vq_prep<<<KDIM / 16, 256, 0, stream>>>(emb, Ef, me2h, out);
    vq_main<<<NTOT / BN, 256, 0, stream>>>(in, emb, Ef, me2h, out);
}

// Round 2
// 141.653 us; speedup vs baseline: 1.5809x; 1.5809x over previous
//
#include <hip/hip_runtime.h>
#include <hip/hip_fp16.h>

// Problem: inputs (8, 64, 16, 32, 32) fp32, embedding (1024, 64) fp32
#define THW    16384
#define NTOT   131072
#define KDIM   1024
#define CDIM   64
#define QELEMS 8388608          // 8*64*16*32*32
#define LOSS_OFF 8388608
#define IDX_OFF  8388610
#define BN     128              // queries per block (4 waves x 32 queries)

typedef _Float16 half8   __attribute__((ext_vector_type(8)));
typedef _Float16 half4_t __attribute__((ext_vector_type(4)));
typedef float    f32x4   __attribute__((ext_vector_type(4)));

// ---- prep: zero losses; split E into fp16 hi/lo (lo scaled 2^12) into ONE
// interleaved buffer Ef[tile][slot][lane][8], slots = {h.ch0, h.ch1, l.ch0,
// l.ch1}, so the main loop's 4 A-loads share a single base pointer with
// 0/1024/2048/3072 B immediate offsets. lane = lq*16 + ln, code row =
// tile*16 + ln, c = ch*32 + lq*8 + j.
// Stores me2h[row] = -0.5*||e||^2 (seed for the hh MFMA chain).
__global__ __launch_bounds__(256) void vq_prep(const float* __restrict__ emb,
        _Float16* __restrict__ Ef, float* __restrict__ me2h,
        float* __restrict__ out) {
    const int t = threadIdx.x;
    if (blockIdx.x == 0 && t == 0) { out[LOSS_OFF] = 0.f; out[LOSS_OFF + 1] = 0.f; }
    const int ln   = t >> 4;
    const int g    = t & 15;
    const int tile = blockIdx.x;
    const int row  = tile * 16 + ln;
    const int c0   = g * 4;
    float4 v = *(const float4*)(emb + (size_t)row * CDIM + c0);
    const float xs[4] = {v.x, v.y, v.z, v.w};
    half4_t h, l;
    float s = 0.f;
    #pragma unroll
    for (int j = 0; j < 4; ++j) {
        const _Float16 hj = (_Float16)xs[j];
        const _Float16 lj = (_Float16)((xs[j] - (float)hj) * 4096.0f);
        h[j] = hj; l[j] = lj;
        s = fmaf(xs[j], xs[j], s);
    }
    const int ch = c0 >> 5;
    const int lq = (c0 & 31) >> 3;
    const int j0 = c0 & 7;
    const int fl = lq * 16 + ln;
    *(half4_t*)(Ef + (((size_t)tile * 4 + ch)     * 64 + fl) * 8 + j0) = h;
    *(half4_t*)(Ef + (((size_t)tile * 4 + 2 + ch) * 64 + fl) * 8 + j0) = l;
    #pragma unroll
    for (int off = 1; off < 16; off <<= 1) s += __shfl_xor(s, off, 64);
    if (g == 0) me2h[row] = -0.5f * s;
}

// ---- main: 4 waves share one tile stream; split MFMA chains; s-max fold.
// launch_bounds(256,4): grid is exactly 4 blocks/CU -> all blocks resident,
// no 1-block tail (LDS 36864*4 = 147456 <= 160K, VGPR ~56 << 128).
__global__ __launch_bounds__(256, 4) void vq_main(const float* __restrict__ in,
        const float* __restrict__ emb,
        const _Float16* __restrict__ Ef,
        const float* __restrict__ me2h, float* __restrict__ out) {

    __shared__ char smem[36416];
    float (*Xs)[68] = (float (*)[68])smem;                 // [128][68] = 34816 B
    float (*Q)[68]  = (float (*)[68])smem;                 // epilogue alias
    float* x2p  = (float*)(smem + 34816);                  // [2][128]
    int*   idxs = (int*)(smem + 35840);                    // [128]
    float* wsum = (float*)(smem + 36352);                  // [4]

    const int tid  = threadIdx.x;
    const int n0   = blockIdx.x * BN;
    const int bb   = n0 >> 14;
    const int thw0 = n0 & (THW - 1);
    const float* inb = in  + (size_t)bb * CDIM * THW + thw0;
    float*      outb = out + (size_t)bb * CDIM * THW + thw0;

    // ---- stage X tile ([n][c] transpose) + ||x||^2 partials ----
    {
        const int nl = tid & 127;
        const int hf = tid >> 7;
        float s = 0.f;
        #pragma unroll 8
        for (int r = 0; r < 32; ++r) {
            const int c = hf * 32 + r;
            const float x = inb[(size_t)c * THW + nl];
            Xs[nl][c] = x;
            s = fmaf(x, x, s);
        }
        x2p[hf * 128 + nl] = s;
    }
    __syncthreads();

    const int lane = tid & 63;
    const int w    = tid >> 6;      // wave owns queries w*32 .. w*32+31
    const int ln   = lane & 15;
    const int lq   = lane >> 4;

    // ---- B fragments (fp16 hi/lo), register-resident ----
    half8 Bh[2][2], Bl[2][2];
    #pragma unroll
    for (int qg = 0; qg < 2; ++qg) {
        const int q = w * 32 + qg * 16 + ln;
        #pragma unroll
        for (int ch = 0; ch < 2; ++ch) {
            const float* xp = &Xs[q][ch * 32 + lq * 8];
            const float4 xa = *(const float4*)(xp);
            const float4 xb = *(const float4*)(xp + 4);
            const float xv[8] = {xa.x, xa.y, xa.z, xa.w, xb.x, xb.y, xb.z, xb.w};
            #pragma unroll
            for (int j = 0; j < 8; ++j) {
                const _Float16 h = (_Float16)xv[j];
                const _Float16 l = (_Float16)((xv[j] - (float)h) * 4096.0f);
                Bh[qg][ch][j] = h;
                Bl[qg][ch][j] = l;
            }
        }
    }

    // maximize s = x.e - 0.5*||e||^2  (argmax s == argmin d, d = -2s)
    float bests[2] = {-3.4e38f, -3.4e38f};
    int   besti[2] = {0, 0};

    const half8* pa  = (const half8*)Ef + lane;     // tile m at +m*256
    const f32x4* pe4 = (const f32x4*)me2h + lq;     // tile m at +m*4

    // depth-1 prefetch, 2 buffers; slots at +0/64/128/192 half8s from one base
    half8 Ah0[2], Ah1[2], Al0[2], Al1[2];
    f32x4 e2r[2];
    Ah0[0] = pa[0];   Ah1[0] = pa[64];
    Al0[0] = pa[128]; Al1[0] = pa[192];
    e2r[0] = pe4[0];

    #pragma unroll 2
    for (int m = 0; m < 64; ++m) {
        const int cur = m & 1;
        const int nxt = cur ^ 1;
        if (m < 63) {
            const size_t o = (size_t)(m + 1) * 256;
            Ah0[nxt] = pa[o];       Ah1[nxt] = pa[o + 64];
            Al0[nxt] = pa[o + 128]; Al1[nxt] = pa[o + 192];
            e2r[nxt] = pe4[(m + 1) * 4];
        }
        #pragma unroll
        for (int qg = 0; qg < 2; ++qg) {
            // cross terms (scaled 2^12): two independent 2-deep chains
            f32x4 a1 = {0.f, 0.f, 0.f, 0.f};
            f32x4 b1 = {0.f, 0.f, 0.f, 0.f};
            a1 = __builtin_amdgcn_mfma_f32_16x16x32_f16(Ah0[cur], Bl[qg][0], a1, 0, 0, 0);
            b1 = __builtin_amdgcn_mfma_f32_16x16x32_f16(Al0[cur], Bh[qg][0], b1, 0, 0, 0);
            a1 = __builtin_amdgcn_mfma_f32_16x16x32_f16(Ah1[cur], Bl[qg][1], a1, 0, 0, 0);
            b1 = __builtin_amdgcn_mfma_f32_16x16x32_f16(Al1[cur], Bh[qg][1], b1, 0, 0, 0);
            // seed hh-chain with 2^-12*(a1+b1) - 0.5*||e||^2
            f32x4 c0;
            #pragma unroll
            for (int r = 0; r < 4; ++r)
                c0[r] = fmaf(2.44140625e-4f, a1[r] + b1[r], e2r[cur][r]);
            c0 = __builtin_amdgcn_mfma_f32_16x16x32_f16(Ah0[cur], Bh[qg][0], c0, 0, 0, 0);
            c0 = __builtin_amdgcn_mfma_f32_16x16x32_f16(Ah1[cur], Bh[qg][1], c0, 0, 0, 0);
            // fold: bare compare (ascending k, strict > keeps lowest k)
            #pragma unroll
            for (int r = 0; r < 4; ++r) {
                const int kg = m * 16 + lq * 4 + r;
                if (c0[r] > bests[qg]) { bests[qg] = c0[r]; besti[qg] = kg; }
            }
        }
    }

    // ---- wave-internal argmax reduce across the 4 row-quads ----
    #pragma unroll
    for (int qg = 0; qg < 2; ++qg) {
        #pragma unroll
        for (int msk = 16; msk <= 32; msk <<= 1) {
            const float ov = __shfl_xor(bests[qg], msk, 64);
            const int   oi = __shfl_xor(besti[qg], msk, 64);
            if (ov > bests[qg] || (ov == bests[qg] && oi < besti[qg])) {
                bests[qg] = ov; besti[qg] = oi;
            }
        }
    }
    float lsum = 0.f;
    if (lq == 0) {
        #pragma unroll
        for (int qg = 0; qg < 2; ++qg) {
            const int q = w * 32 + qg * 16 + ln;
            idxs[q] = besti[qg];
            out[IDX_OFF + n0 + q] = (float)besti[qg];
            // d = -2*s ; loss term = d + ||x||^2
            lsum += fmaf(-2.0f, bests[qg], x2p[q] + x2p[128 + q]);
        }
    }
    #pragma unroll
    for (int off = 32; off > 0; off >>= 1) lsum += __shfl_down(lsum, off, 64);
    if (lane == 0) wsum[w] = lsum;
    __syncthreads();
    if (tid == 0) {
        const float s = wsum[0] + wsum[1] + wsum[2] + wsum[3];
        atomicAdd(&out[LOSS_OFF],     s * (1.0f  / (float)QELEMS));
        atomicAdd(&out[LOSS_OFF + 1], s * (0.25f / (float)QELEMS));
    }

    // ---- epilogue: gather code rows into LDS (Q aliases dead Xs), transpose-write ----
    {
        const int q  = tid >> 1;
        const int hf = tid & 1;
        const float* er = emb + (size_t)idxs[q] * CDIM + hf * 32;
        #pragma unroll
        for (int j = 0; j < 8; ++j) {
            const float4 v = *(const float4*)(er + 4 * j);
            *(float4*)(&Q[q][hf * 32 + 4 * j]) = v;
        }
    }
    __syncthreads();
    {
        const int nl = tid & 127;
        const int cb = tid >> 7;
        #pragma unroll 8
        for (int r = 0; r < 32; ++r) {
            const int c = 2 * r + cb;
            outb[(size_t)c * THW + nl] = Q[nl][c];
        }
    }
}

extern "C" void kernel_launch(void* const* d_in, const int* in_sizes, int n_in,
                              void* d_out, int out_size, void* d_ws, size_t ws_size,
                              hipStream_t stream) {
    const float* in  = (const float*)d_in[0];   // (8, 64, 16, 32, 32) fp32
    const float* emb = (const float*)d_in[1];   // (1024, 64) fp32
    float* out = (float*)d_out;
    _Float16* Ef   = (_Float16*)d_ws;                       // 64 tiles * 4 * 64 * 8 halves = 256 KB
    float*    me2h = (float*)((char*)d_ws + 262144);        // 1024 floats = -0.5*||e||^2

    vq_prep<<<KDIM / 16, 256, 0, stream>>>(emb, Ef, me2h, out);
    vq_main<<<NTOT / BN, 256, 0, stream>>>(in, emb, Ef, me2h, out);
}

// Round 3
// 136.729 us; speedup vs baseline: 1.6379x; 1.0360x over previous
//
#include <hip/hip_runtime.h>
#include <hip/hip_fp16.h>

// Problem: inputs (8, 64, 16, 32, 32) fp32, embedding (1024, 64) fp32
#define THW    16384
#define NTOT   131072
#define KDIM   1024
#define CDIM   64
#define QELEMS 8388608          // 8*64*16*32*32
#define LOSS_OFF 8388608
#define IDX_OFF  8388610
#define BN     128              // queries per block (4 waves x 32 queries)

typedef _Float16 half8   __attribute__((ext_vector_type(8)));
typedef _Float16 half4_t __attribute__((ext_vector_type(4)));
typedef float    f32x4   __attribute__((ext_vector_type(4)));

// ---- prep: zero losses; split E into fp16 hi/lo (lo scaled 2^12) into ONE
// interleaved buffer Ef[tile][slot][lane][8], slots = {h.ch0, h.ch1, l.ch0,
// l.ch1}; tile = 4 KB, linear in the exact lane order vq_main's ds_reads use,
// so global_load_lds (wave-uniform base + lane*16) can stage it untouched.
// me2h[row] = -2048*||e||^2  (= 4096 * (-0.5||e||^2)): pre-scaled so it seeds
// the 2^12-scaled cross-term accumulator directly from the load.
__global__ __launch_bounds__(256) void vq_prep(const float* __restrict__ emb,
        _Float16* __restrict__ Ef, float* __restrict__ me2h,
        float* __restrict__ out) {
    const int t = threadIdx.x;
    if (blockIdx.x == 0 && t == 0) { out[LOSS_OFF] = 0.f; out[LOSS_OFF + 1] = 0.f; }
    const int ln   = t >> 4;
    const int g    = t & 15;
    const int tile = blockIdx.x;
    const int row  = tile * 16 + ln;
    const int c0   = g * 4;
    float4 v = *(const float4*)(emb + (size_t)row * CDIM + c0);
    const float xs[4] = {v.x, v.y, v.z, v.w};
    half4_t h, l;
    float s = 0.f;
    #pragma unroll
    for (int j = 0; j < 4; ++j) {
        const _Float16 hj = (_Float16)xs[j];
        const _Float16 lj = (_Float16)((xs[j] - (float)hj) * 4096.0f);
        h[j] = hj; l[j] = lj;
        s = fmaf(xs[j], xs[j], s);
    }
    const int ch = c0 >> 5;
    const int lq = (c0 & 31) >> 3;
    const int j0 = c0 & 7;
    const int fl = lq * 16 + ln;
    *(half4_t*)(Ef + (((size_t)tile * 4 + ch)     * 64 + fl) * 8 + j0) = h;
    *(half4_t*)(Ef + (((size_t)tile * 4 + 2 + ch) * 64 + fl) * 8 + j0) = l;
    #pragma unroll
    for (int off = 1; off < 16; off <<= 1) s += __shfl_xor(s, off, 64);
    if (g == 0) me2h[row] = -2048.0f * s;
}

// ---- main: block-cooperative async LDS staging of the Ef stream.
// Per 4-tile step: issue global_load_lds for next step (16 KB, all 256
// threads, 4x16B each), ds_read current tiles (conflict-free lane*16),
// MFMA+fold, one __syncthreads (drains vmcnt -> next buffer ready).
// L2 traffic for Ef drops 4x vs per-wave loads; waves stay lockstep.
__global__ __launch_bounds__(256, 4) void vq_main(const float* __restrict__ in,
        const float* __restrict__ emb,
        const _Float16* __restrict__ Ef,
        const float* __restrict__ me2h, float* __restrict__ out) {

    __shared__ char smem[36864];
    float (*Xs)[68] = (float (*)[68])smem;                 // staging/B-build
    float (*Q)[68]  = (float (*)[68])smem;                 // epilogue alias
    // loop phase alias: smem[0..32768) = A-tile double buffer (2 x 16 KB)
    float* x2p  = (float*)(smem + 34816);                  // [2][128]
    int*   idxs = (int*)(smem + 35840);                    // [128]
    float* wsum = (float*)(smem + 36352);                  // [4]

    const int tid  = threadIdx.x;
    const int n0   = blockIdx.x * BN;
    const int bb   = n0 >> 14;
    const int thw0 = n0 & (THW - 1);
    const float* inb = in  + (size_t)bb * CDIM * THW + thw0;
    float*      outb = out + (size_t)bb * CDIM * THW + thw0;

    // ---- stage X tile ([n][c] transpose) + ||x||^2 partials ----
    {
        const int nl = tid & 127;
        const int hf = tid >> 7;
        float s = 0.f;
        #pragma unroll 8
        for (int r = 0; r < 32; ++r) {
            const int c = hf * 32 + r;
            const float x = inb[(size_t)c * THW + nl];
            Xs[nl][c] = x;
            s = fmaf(x, x, s);
        }
        x2p[hf * 128 + nl] = s;
    }
    __syncthreads();

    const int lane = tid & 63;
    const int w    = tid >> 6;      // wave owns queries w*32 .. w*32+31
    const int ln   = lane & 15;
    const int lq   = lane >> 4;

    // ---- B fragments (fp16 hi/lo), register-resident ----
    half8 Bh[2][2], Bl[2][2];
    #pragma unroll
    for (int qg = 0; qg < 2; ++qg) {
        const int q = w * 32 + qg * 16 + ln;
        #pragma unroll
        for (int ch = 0; ch < 2; ++ch) {
            const float* xp = &Xs[q][ch * 32 + lq * 8];
            const float4 xa = *(const float4*)(xp);
            const float4 xb = *(const float4*)(xp + 4);
            const float xv[8] = {xa.x, xa.y, xa.z, xa.w, xb.x, xb.y, xb.z, xb.w};
            #pragma unroll
            for (int j = 0; j < 8; ++j) {
                const _Float16 h = (_Float16)xv[j];
                const _Float16 l = (_Float16)((xv[j] - (float)h) * 4096.0f);
                Bh[qg][ch][j] = h;
                Bl[qg][ch][j] = l;
            }
        }
    }
    __syncthreads();    // Xs dead -> smem[0..32K) becomes the A double buffer

    // per-thread global source base for staging (lane*16 matches the HW's
    // wave-uniform-base + lane*16 LDS write pattern)
    const char* Efb = (const char*)Ef + (size_t)(w * 1024 + lane * 16);

    // prologue: stage step 0 (tiles 0..3) into buffer 0
    #pragma unroll
    for (int i = 0; i < 4; ++i)
        __builtin_amdgcn_global_load_lds(
            (const unsigned int*)(Efb + i * 4096),
            (unsigned int*)(smem + w * 1024 + i * 4096), 16, 0, 0);
    __syncthreads();

    // maximize s = x.e - 0.5*||e||^2  (argmax s == argmin d, d = -2s)
    float bests[2] = {-3.4e38f, -3.4e38f};
    int   besti[2] = {0, 0};
    const f32x4* pe4 = (const f32x4*)me2h + lq;     // tile m at +m*4

    #pragma unroll 2
    for (int s = 0; s < 16; ++s) {
        const int cur = s & 1;
        if (s < 15) {   // issue next step's staging first: overlaps compute
            const char* g = Efb + (size_t)(s + 1) * 16384;
            char* l = smem + (cur ^ 1) * 16384 + w * 1024;
            #pragma unroll
            for (int i = 0; i < 4; ++i)
                __builtin_amdgcn_global_load_lds(
                    (const unsigned int*)(g + i * 4096),
                    (unsigned int*)(l + i * 4096), 16, 0, 0);
        }
        // e2 seeds for the 4 tiles (pre-scaled x4096; 16-lane broadcast)
        f32x4 e2s[4];
        #pragma unroll
        for (int tt = 0; tt < 4; ++tt) e2s[tt] = pe4[s * 16 + tt * 4];

        #pragma unroll
        for (int tt = 0; tt < 4; ++tt) {
            const half8* A = (const half8*)(smem + cur * 16384 + tt * 4096);
            const half8 ah0 = A[lane];
            const half8 ah1 = A[64 + lane];
            const half8 al0 = A[128 + lane];
            const half8 al1 = A[192 + lane];
            const int kb = (s * 4 + tt) * 16;       // wave-uniform (SALU)
            #pragma unroll
            for (int qg = 0; qg < 2; ++qg) {
                // cross terms, accumulator seeded by 4096*(-0.5||e||^2)
                f32x4 a1 = e2s[tt];
                a1 = __builtin_amdgcn_mfma_f32_16x16x32_f16(ah0, Bl[qg][0], a1, 0, 0, 0);
                a1 = __builtin_amdgcn_mfma_f32_16x16x32_f16(al0, Bh[qg][0], a1, 0, 0, 0);
                a1 = __builtin_amdgcn_mfma_f32_16x16x32_f16(ah1, Bl[qg][1], a1, 0, 0, 0);
                a1 = __builtin_amdgcn_mfma_f32_16x16x32_f16(al1, Bh[qg][1], a1, 0, 0, 0);
                // c0 = 2^-12 * a1 = -0.5||e||^2 + cross ; then hh chain
                f32x4 c0;
                #pragma unroll
                for (int r = 0; r < 4; ++r) c0[r] = 2.44140625e-4f * a1[r];
                c0 = __builtin_amdgcn_mfma_f32_16x16x32_f16(ah0, Bh[qg][0], c0, 0, 0, 0);
                c0 = __builtin_amdgcn_mfma_f32_16x16x32_f16(ah1, Bh[qg][1], c0, 0, 0, 0);
                // fold: ascending k, strict > keeps lowest; index stored as
                // wave-uniform kb+r (SGPR src), +lq*4 applied after the loop
                #pragma unroll
                for (int r = 0; r < 4; ++r)
                    if (c0[r] > bests[qg]) { bests[qg] = c0[r]; besti[qg] = kb + r; }
            }
        }
        __syncthreads();    // next buffer staged (vmcnt drained) + reads done
    }

    besti[0] += lq * 4;     // full code index = m*16 + lq*4 + r
    besti[1] += lq * 4;

    // ---- wave-internal argmax reduce across the 4 row-quads ----
    #pragma unroll
    for (int qg = 0; qg < 2; ++qg) {
        #pragma unroll
        for (int msk = 16; msk <= 32; msk <<= 1) {
            const float ov = __shfl_xor(bests[qg], msk, 64);
            const int   oi = __shfl_xor(besti[qg], msk, 64);
            if (ov > bests[qg] || (ov == bests[qg] && oi < besti[qg])) {
                bests[qg] = ov; besti[qg] = oi;
            }
        }
    }
    float lsum = 0.f;
    if (lq == 0) {
        #pragma unroll
        for (int qg = 0; qg < 2; ++qg) {
            const int q = w * 32 + qg * 16 + ln;
            idxs[q] = besti[qg];
            out[IDX_OFF + n0 + q] = (float)besti[qg];
            // d = -2*s ; loss term = d + ||x||^2
            lsum += fmaf(-2.0f, bests[qg], x2p[q] + x2p[128 + q]);
        }
    }
    #pragma unroll
    for (int off = 32; off > 0; off >>= 1) lsum += __shfl_down(lsum, off, 64);
    if (lane == 0) wsum[w] = lsum;
    __syncthreads();
    if (tid == 0) {
        const float s = wsum[0] + wsum[1] + wsum[2] + wsum[3];
        atomicAdd(&out[LOSS_OFF],     s * (1.0f  / (float)QELEMS));
        atomicAdd(&out[LOSS_OFF + 1], s * (0.25f / (float)QELEMS));
    }

    // ---- epilogue: gather code rows into LDS (Q aliases dead bufs), transpose-write ----
    {
        const int q  = tid >> 1;
        const int hf = tid & 1;
        const float* er = emb + (size_t)idxs[q] * CDIM + hf * 32;
        #pragma unroll
        for (int j = 0; j < 8; ++j) {
            const float4 v = *(const float4*)(er + 4 * j);
            *(float4*)(&Q[q][hf * 32 + 4 * j]) = v;
        }
    }
    __syncthreads();
    {
        const int nl = tid & 127;
        const int cb = tid >> 7;
        #pragma unroll 8
        for (int r = 0; r < 32; ++r) {
            const int c = 2 * r + cb;
            outb[(size_t)c * THW + nl] = Q[nl][c];
        }
    }
}

extern "C" void kernel_launch(void* const* d_in, const int* in_sizes, int n_in,
                              void* d_out, int out_size, void* d_ws, size_t ws_size,
                              hipStream_t stream) {
    const float* in  = (const float*)d_in[0];   // (8, 64, 16, 32, 32) fp32
    const float* emb = (const float*)d_in[1];   // (1024, 64) fp32
    float* out = (float*)d_out;
    _Float16* Ef   = (_Float16*)d_ws;                       // 64 tiles * 4 KB = 256 KB
    float*    me2h = (float*)((char*)d_ws + 262144);        // 1024 floats = -2048*||e||^2

    vq_prep<<<KDIM / 16, 256, 0, stream>>>(emb, Ef, me2h, out);
    vq_main<<<NTOT / BN, 256, 0, stream>>>(in, emb, Ef, me2h, out);
}

// Round 4
// 134.906 us; speedup vs baseline: 1.6600x; 1.0135x over previous
//
#include <hip/hip_runtime.h>
#include <hip/hip_fp16.h>

// Problem: inputs (8, 64, 16, 32, 32) fp32, embedding (1024, 64) fp32
#define THW    16384
#define NTOT   131072
#define KDIM   1024
#define CDIM   64
#define QELEMS 8388608          // 8*64*16*32*32
#define LOSS_OFF 8388608
#define IDX_OFF  8388610
#define BN     128              // queries per block (4 waves x 32 queries)

typedef _Float16 half8   __attribute__((ext_vector_type(8)));
typedef _Float16 half4_t __attribute__((ext_vector_type(4)));
typedef float    f32x4   __attribute__((ext_vector_type(4)));

// ---- prep: zero losses; split E into fp16 hi/lo (lo scaled 2^12) into ONE
// interleaved buffer Ef[tile][slot][lane][8], slots = {h.ch0, h.ch1, l.ch0,
// l.ch1}; tile = 4 KB, linear in the exact lane order vq_main's ds_reads use,
// so global_load_lds (wave-uniform base + lane*16) can stage it untouched.
// me2h[row] = -0.5*||e||^2 (seeds the hh MFMA chain directly).
__global__ __launch_bounds__(256) void vq_prep(const float* __restrict__ emb,
        _Float16* __restrict__ Ef, float* __restrict__ me2h,
        float* __restrict__ out) {
    const int t = threadIdx.x;
    if (blockIdx.x == 0 && t == 0) { out[LOSS_OFF] = 0.f; out[LOSS_OFF + 1] = 0.f; }
    const int ln   = t >> 4;
    const int g    = t & 15;
    const int tile = blockIdx.x;
    const int row  = tile * 16 + ln;
    const int c0   = g * 4;
    float4 v = *(const float4*)(emb + (size_t)row * CDIM + c0);
    const float xs[4] = {v.x, v.y, v.z, v.w};
    half4_t h, l;
    float s = 0.f;
    #pragma unroll
    for (int j = 0; j < 4; ++j) {
        const _Float16 hj = (_Float16)xs[j];
        const _Float16 lj = (_Float16)((xs[j] - (float)hj) * 4096.0f);
        h[j] = hj; l[j] = lj;
        s = fmaf(xs[j], xs[j], s);
    }
    const int ch = c0 >> 5;
    const int lq = (c0 & 31) >> 3;
    const int j0 = c0 & 7;
    const int fl = lq * 16 + ln;
    *(half4_t*)(Ef + (((size_t)tile * 4 + ch)     * 64 + fl) * 8 + j0) = h;
    *(half4_t*)(Ef + (((size_t)tile * 4 + 2 + ch) * 64 + fl) * 8 + j0) = l;
    #pragma unroll
    for (int off = 1; off < 16; off <<= 1) s += __shfl_xor(s, off, 64);
    if (g == 0) me2h[row] = -0.5f * s;
}

// ---- main: counted-vmcnt 3-buffer pipeline (never drains in steady loop),
// 4 independent MFMA chains per wave (hh 2-dep || cross 4-dep, per qg),
// e2 seeds broadcast from LDS. LDS 53248 B -> 3 blocks/CU.
__global__ __launch_bounds__(256, 3) void vq_main(const float* __restrict__ in,
        const float* __restrict__ emb,
        const _Float16* __restrict__ Ef,
        const float* __restrict__ me2h, float* __restrict__ out) {

    __shared__ char smem[53248];
    // phase 1: Xs[128][68] @ 0 (34816 B)
    // loop:    buf0/1/2 @ 0/16384/32768 (16 KB each); me2l @ 49152 (4 KB)
    // post:    idxs @ 0 (512 B), wsum @ 512, Q[128][68] @ 1024
    float (*Xs)[68] = (float (*)[68])smem;
    float (*Q)[68]  = (float (*)[68])(smem + 1024);
    int*   idxs = (int*)smem;
    float* wsum = (float*)(smem + 512);
    const char* me2l = (const char*)smem + 49152;

    const int tid  = threadIdx.x;
    const int lane = tid & 63;
    const int w    = tid >> 6;      // wave owns queries w*32 .. w*32+31
    const int ln   = lane & 15;
    const int lq   = lane >> 4;

    const int n0   = blockIdx.x * BN;
    const int bb   = n0 >> 14;
    const int thw0 = n0 & (THW - 1);
    const float* inb = in  + (size_t)bb * CDIM * THW + thw0;
    float*      outb = out + (size_t)bb * CDIM * THW + thw0;

    // issue me2h -> LDS copy first (4 KB; lands during X staging; me2l region
    // does not overlap Xs). In-order vmcnt retirement guarantees it completes
    // before any loop-step wait admits it.
    __builtin_amdgcn_global_load_lds(
        (const unsigned int*)((const char*)me2h + w * 1024 + lane * 16),
        (unsigned int*)(smem + 49152 + w * 1024), 16, 0, 0);

    // ---- stage X tile ([n][c] transpose) ----
    {
        const int nl = tid & 127;
        const int hf = tid >> 7;
        #pragma unroll 8
        for (int r = 0; r < 32; ++r) {
            const int c = hf * 32 + r;
            Xs[nl][c] = inb[(size_t)c * THW + nl];
        }
    }
    __syncthreads();

    // ---- B fragments (fp16 hi/lo) + ||x||^2 in registers ----
    half8 Bh[2][2], Bl[2][2];
    float x2r[2];
    #pragma unroll
    for (int qg = 0; qg < 2; ++qg) {
        const int q = w * 32 + qg * 16 + ln;
        float s = 0.f;
        #pragma unroll
        for (int ch = 0; ch < 2; ++ch) {
            const float* xp = &Xs[q][ch * 32 + lq * 8];
            const float4 xa = *(const float4*)(xp);
            const float4 xb = *(const float4*)(xp + 4);
            const float xv[8] = {xa.x, xa.y, xa.z, xa.w, xb.x, xb.y, xb.z, xb.w};
            #pragma unroll
            for (int j = 0; j < 8; ++j) {
                const _Float16 h = (_Float16)xv[j];
                const _Float16 l = (_Float16)((xv[j] - (float)h) * 4096.0f);
                Bh[qg][ch][j] = h;
                Bl[qg][ch][j] = l;
                s = fmaf(xv[j], xv[j], s);
            }
        }
        s += __shfl_xor(s, 16, 64);     // fold the 4 lq-quads: full ||x||^2
        s += __shfl_xor(s, 32, 64);
        x2r[qg] = s;
    }
    __syncthreads();    // Xs dead -> smem[0..48K) becomes the A triple buffer

    const char* Efb = (const char*)Ef + (size_t)(w * 1024 + lane * 16);

    float bests[2] = {-3.4e38f, -3.4e38f};
    int   besti[2] = {0, 0};

#define STAGE(K, BI)                                                          \
    {   const char* gsrc = Efb + (size_t)(K) * 16384;                         \
        char* ldst = smem + (BI) * 16384 + w * 1024;                          \
        __builtin_amdgcn_global_load_lds((const unsigned int*)(gsrc),         \
                (unsigned int*)(ldst), 16, 0, 0);                             \
        __builtin_amdgcn_global_load_lds((const unsigned int*)(gsrc + 4096),  \
                (unsigned int*)(ldst + 4096), 16, 0, 0);                      \
        __builtin_amdgcn_global_load_lds((const unsigned int*)(gsrc + 8192),  \
                (unsigned int*)(ldst + 8192), 16, 0, 0);                      \
        __builtin_amdgcn_global_load_lds((const unsigned int*)(gsrc + 12288), \
                (unsigned int*)(ldst + 12288), 16, 0, 0);                     \
    }

#define COMPUTE(K, BI)                                                        \
    {   const char* bufb = smem + (BI) * 16384;                               \
        _Pragma("unroll")                                                     \
        for (int tt = 0; tt < 4; ++tt) {                                      \
            const half8* A = (const half8*)(bufb + tt * 4096);                \
            const half8 ah0 = A[lane];                                        \
            const half8 ah1 = A[64 + lane];                                   \
            const half8 al0 = A[128 + lane];                                  \
            const half8 al1 = A[192 + lane];                                  \
            const f32x4 e2v = *(const f32x4*)(me2l + ((K)*4 + tt) * 64 + lq * 16); \
            const int kb = ((K)*4 + tt) * 16;                                 \
            _Pragma("unroll")                                                 \
            for (int qg = 0; qg < 2; ++qg) {                                  \
                f32x4 hh = e2v;                                               \
                hh = __builtin_amdgcn_mfma_f32_16x16x32_f16(ah0, Bh[qg][0], hh, 0, 0, 0); \
                hh = __builtin_amdgcn_mfma_f32_16x16x32_f16(ah1, Bh[qg][1], hh, 0, 0, 0); \
                f32x4 cr = {0.f, 0.f, 0.f, 0.f};                              \
                cr = __builtin_amdgcn_mfma_f32_16x16x32_f16(ah0, Bl[qg][0], cr, 0, 0, 0); \
                cr = __builtin_amdgcn_mfma_f32_16x16x32_f16(al0, Bh[qg][0], cr, 0, 0, 0); \
                cr = __builtin_amdgcn_mfma_f32_16x16x32_f16(ah1, Bl[qg][1], cr, 0, 0, 0); \
                cr = __builtin_amdgcn_mfma_f32_16x16x32_f16(al1, Bh[qg][1], cr, 0, 0, 0); \
                _Pragma("unroll")                                             \
                for (int r = 0; r < 4; ++r) {                                 \
                    const float cv = fmaf(2.44140625e-4f, cr[r], hh[r]);      \
                    if (cv > bests[qg]) { bests[qg] = cv; besti[qg] = kb + r; } \
                }                                                             \
            }                                                                 \
        }                                                                     \
    }

#define WAIT4 asm volatile("s_waitcnt vmcnt(4)" ::: "memory")
#define WAIT0 asm volatile("s_waitcnt vmcnt(0)" ::: "memory")
#define BAR   __builtin_amdgcn_s_barrier()

    // prologue: stage steps 0,1
    STAGE(0, 0)
    STAGE(1, 1)

    // steady steps: wait my stage(s) landed (vmcnt(4): stage(s+1) in flight),
    // barrier (everyone's stage(s) landed; everyone done reading the buffer
    // stage(s+2) will overwrite), issue stage(s+2), compute buf[s%3].
    WAIT4; BAR; STAGE(2, 2)  COMPUTE(0, 0)
    WAIT4; BAR; STAGE(3, 0)  COMPUTE(1, 1)
    WAIT4; BAR; STAGE(4, 1)  COMPUTE(2, 2)
    WAIT4; BAR; STAGE(5, 2)  COMPUTE(3, 0)
    WAIT4; BAR; STAGE(6, 0)  COMPUTE(4, 1)
    WAIT4; BAR; STAGE(7, 1)  COMPUTE(5, 2)
    WAIT4; BAR; STAGE(8, 2)  COMPUTE(6, 0)
    WAIT4; BAR; STAGE(9, 0)  COMPUTE(7, 1)
    WAIT4; BAR; STAGE(10, 1) COMPUTE(8, 2)
    WAIT4; BAR; STAGE(11, 2) COMPUTE(9, 0)
    WAIT4; BAR; STAGE(12, 0) COMPUTE(10, 1)
    WAIT4; BAR; STAGE(13, 1) COMPUTE(11, 2)
    WAIT4; BAR; STAGE(14, 2) COMPUTE(12, 0)
    WAIT4; BAR; STAGE(15, 0) COMPUTE(13, 1)
    WAIT4; BAR;              COMPUTE(14, 2)
    WAIT0; BAR;              COMPUTE(15, 0)

    __syncthreads();    // all waves done with bufs before idxs/Q overwrite

    besti[0] += lq * 4;     // full code index = m*16 + lq*4 + r
    besti[1] += lq * 4;

    // ---- wave-internal argmax reduce across the 4 row-quads ----
    #pragma unroll
    for (int qg = 0; qg < 2; ++qg) {
        #pragma unroll
        for (int msk = 16; msk <= 32; msk <<= 1) {
            const float ov = __shfl_xor(bests[qg], msk, 64);
            const int   oi = __shfl_xor(besti[qg], msk, 64);
            if (ov > bests[qg] || (ov == bests[qg] && oi < besti[qg])) {
                bests[qg] = ov; besti[qg] = oi;
            }
        }
    }
    float lsum = 0.f;
    if (lq == 0) {
        #pragma unroll
        for (int qg = 0; qg < 2; ++qg) {
            const int q = w * 32 + qg * 16 + ln;
            idxs[q] = besti[qg];
            out[IDX_OFF + n0 + q] = (float)besti[qg];
            // d = -2*s ; loss term = d + ||x||^2
            lsum += fmaf(-2.0f, bests[qg], x2r[qg]);
        }
    }
    #pragma unroll
    for (int off = 32; off > 0; off >>= 1) lsum += __shfl_down(lsum, off, 64);
    if (lane == 0) wsum[w] = lsum;
    __syncthreads();
    if (tid == 0) {
        const float s = wsum[0] + wsum[1] + wsum[2] + wsum[3];
        atomicAdd(&out[LOSS_OFF],     s * (1.0f  / (float)QELEMS));
        atomicAdd(&out[LOSS_OFF + 1], s * (0.25f / (float)QELEMS));
    }

    // ---- epilogue: gather code rows into LDS, transpose-write ----
    {
        const int q  = tid >> 1;
        const int hf = tid & 1;
        const float* er = emb + (size_t)idxs[q] * CDIM + hf * 32;
        #pragma unroll
        for (int j = 0; j < 8; ++j) {
            const float4 v = *(const float4*)(er + 4 * j);
            *(float4*)(&Q[q][hf * 32 + 4 * j]) = v;
        }
    }
    __syncthreads();
    {
        const int nl = tid & 127;
        const int cb = tid >> 7;
        #pragma unroll 8
        for (int r = 0; r < 32; ++r) {
            const int c = 2 * r + cb;
            outb[(size_t)c * THW + nl] = Q[nl][c];
        }
    }
#undef STAGE
#undef COMPUTE
#undef WAIT4
#undef WAIT0
#undef BAR
}

extern "C" void kernel_launch(void* const* d_in, const int* in_sizes, int n_in,
                              void* d_out, int out_size, void* d_ws, size_t ws_size,
                              hipStream_t stream) {
    const float* in  = (const float*)d_in[0];   // (8, 64, 16, 32, 32) fp32
    const float* emb = (const float*)d_in[1];   // (1024, 64) fp32
    float* out = (float*)d_out;
    _Float16* Ef   = (_Float16*)d_ws;                       // 64 tiles * 4 KB = 256 KB
    float*    me2h = (float*)((char*)d_ws + 262144);        // 1024 floats = -0.5*||e||^2

    vq_prep<<<KDIM / 16, 256, 0, stream>>>(emb, Ef, me2h, out);
    vq_main<<<NTOT / BN, 256, 0, stream>>>(in, emb, Ef, me2h, out);
}